// Round 1
// baseline (1455.522 us; speedup 1.0000x reference)
//
#include <hip/hip_runtime.h>

#define D_FEAT 64

// One thread per (edge, feature) pair.
// out[rows[e]*64 + d] += vals[e] * h[cols[e]*64 + d]
__global__ void spmm_atomic_kernel(const float* __restrict__ h,
                                   const float* __restrict__ vals,
                                   const int* __restrict__ rows,
                                   const int* __restrict__ cols,
                                   float* __restrict__ out,
                                   int n_edges) {
    long long tid = (long long)blockIdx.x * blockDim.x + threadIdx.x;
    int e = (int)(tid >> 6);
    int d = (int)(tid & 63);
    if (e >= n_edges) return;
    float v = vals[e];
    int c = cols[e];
    int r = rows[e];
    float m = v * h[(long long)c * D_FEAT + d];
    atomicAdd(&out[(long long)r * D_FEAT + d], m);
}

extern "C" void kernel_launch(void* const* d_in, const int* in_sizes, int n_in,
                              void* d_out, int out_size, void* d_ws, size_t ws_size,
                              hipStream_t stream) {
    const float* x    = (const float*)d_in[0];
    const float* vals = (const float*)d_in[1];
    const int*   rows = (const int*)d_in[2];
    const int*   cols = (const int*)d_in[3];

    int n_nodes = in_sizes[0] / D_FEAT;
    int n_edges = in_sizes[1];

    float* out = (float*)d_out;
    float* ws  = (float*)d_ws;

    size_t buf_bytes = (size_t)n_nodes * D_FEAT * sizeof(float);

    // 5 steps, ping-pong so step 5 lands in d_out:
    // x -> out -> ws -> out -> ws -> out
    float* dsts[5] = {out, ws, out, ws, out};

    long long total_threads = (long long)n_edges * D_FEAT;
    int block = 256;
    int grid = (int)((total_threads + block - 1) / block);

    const float* src = x;
    for (int s = 0; s < 5; ++s) {
        hipMemsetAsync(dsts[s], 0, buf_bytes, stream);
        spmm_atomic_kernel<<<grid, block, 0, stream>>>(src, vals, rows, cols,
                                                       dsts[s], n_edges);
        src = dsts[s];
    }
}

// Round 2
// 579.356 us; speedup vs baseline: 2.5123x; 2.5123x over previous
//
#include <hip/hip_runtime.h>

#define D_FEAT 64

// ---------------- CSR build ----------------

__global__ void hist_kernel(const int* __restrict__ rows, int* __restrict__ cnt, int n_edges) {
    int i = blockIdx.x * blockDim.x + threadIdx.x;
    if (i < n_edges) atomicAdd(&cnt[rows[i]], 1);
}

// Phase A: per-block sums of cnt (256 per block)
__global__ void blocksum_kernel(const int* __restrict__ cnt, int* __restrict__ partial, int n) {
    __shared__ int buf[256];
    int t = threadIdx.x;
    int i = blockIdx.x * 256 + t;
    buf[t] = (i < n) ? cnt[i] : 0;
    __syncthreads();
    for (int s = 128; s > 0; s >>= 1) {
        if (t < s) buf[t] += buf[t + s];
        __syncthreads();
    }
    if (t == 0) partial[blockIdx.x] = buf[0];
}

// Phase B: exclusive scan of partials (single block, nb <= 256)
__global__ void scan_partials_kernel(int* __restrict__ partial, int nb) {
    __shared__ int buf[256];
    int t = threadIdx.x;
    int v = (t < nb) ? partial[t] : 0;
    buf[t] = v;
    __syncthreads();
    for (int off = 1; off < 256; off <<= 1) {
        int add = (t >= off) ? buf[t - off] : 0;
        __syncthreads();
        buf[t] += add;
        __syncthreads();
    }
    if (t < nb) partial[t] = buf[t] - v;  // exclusive
}

// Phase C: per-block inclusive scan + blockbase -> offs (inclusive at i+1) and cursor (exclusive)
__global__ void scan_final_kernel(const int* __restrict__ cnt, const int* __restrict__ partial,
                                  int* __restrict__ offs, int* __restrict__ cursor, int n) {
    __shared__ int buf[256];
    int t = threadIdx.x;
    int i = blockIdx.x * 256 + t;
    int v = (i < n) ? cnt[i] : 0;
    buf[t] = v;
    __syncthreads();
    for (int off = 1; off < 256; off <<= 1) {
        int add = (t >= off) ? buf[t - off] : 0;
        __syncthreads();
        buf[t] += add;
        __syncthreads();
    }
    int incl = buf[t];
    int base = partial[blockIdx.x];
    if (i < n) {
        offs[i + 1] = base + incl;
        cursor[i] = base + incl - v;
    }
    if (i == 0) offs[0] = 0;
}

// Scatter edges into row-sorted (col, val) pairs
__global__ void scatter_kernel(const float* __restrict__ vals, const int* __restrict__ rows,
                               const int* __restrict__ cols, int* __restrict__ cursor,
                               int2* __restrict__ edges, int n_edges) {
    int i = blockIdx.x * blockDim.x + threadIdx.x;
    if (i >= n_edges) return;
    int r = rows[i];
    int pos = atomicAdd(&cursor[r], 1);
    edges[pos] = make_int2(cols[i], __float_as_int(vals[i]));
}

// ---------------- SpMM (no atomics): one wave per row ----------------

__global__ void spmm_csr_kernel(const float* __restrict__ h,
                                const int2* __restrict__ edges,
                                const int* __restrict__ offs,
                                float* __restrict__ out, int n_nodes) {
    int wave = (int)((blockIdx.x * (long long)blockDim.x + threadIdx.x) >> 6);
    int lane = threadIdx.x & 63;
    if (wave >= n_nodes) return;
    int beg = offs[wave];
    int end = offs[wave + 1];
    float acc = 0.f;
    int j = beg;
    for (; j + 1 < end; j += 2) {
        int2 e0 = edges[j];
        int2 e1 = edges[j + 1];
        float h0 = h[(size_t)e0.x * D_FEAT + lane];
        float h1 = h[(size_t)e1.x * D_FEAT + lane];
        acc += __int_as_float(e0.y) * h0;
        acc += __int_as_float(e1.y) * h1;
    }
    if (j < end) {
        int2 e0 = edges[j];
        acc += __int_as_float(e0.y) * h[(size_t)e0.x * D_FEAT + lane];
    }
    out[(size_t)wave * D_FEAT + lane] = acc;
}

// ---------------- fallback (round-1 atomic path) ----------------

__global__ void spmm_atomic_kernel(const float* __restrict__ h,
                                   const float* __restrict__ vals,
                                   const int* __restrict__ rows,
                                   const int* __restrict__ cols,
                                   float* __restrict__ out,
                                   int n_edges) {
    long long tid = (long long)blockIdx.x * blockDim.x + threadIdx.x;
    int e = (int)(tid >> 6);
    int d = (int)(tid & 63);
    if (e >= n_edges) return;
    float m = vals[e] * h[(size_t)cols[e] * D_FEAT + d];
    atomicAdd(&out[(size_t)rows[e] * D_FEAT + d], m);
}

extern "C" void kernel_launch(void* const* d_in, const int* in_sizes, int n_in,
                              void* d_out, int out_size, void* d_ws, size_t ws_size,
                              hipStream_t stream) {
    const float* x    = (const float*)d_in[0];
    const float* vals = (const float*)d_in[1];
    const int*   rows = (const int*)d_in[2];
    const int*   cols = (const int*)d_in[3];

    int n_nodes = in_sizes[0] / D_FEAT;
    int n_edges = in_sizes[1];

    float* out = (float*)d_out;

    size_t buf_bytes = (size_t)n_nodes * D_FEAT * sizeof(float);

    // ws layout (256B-aligned chunks)
    auto align_up = [](size_t v) { return (v + 255) & ~(size_t)255; };
    size_t ping_b    = align_up(buf_bytes);
    size_t cnt_b     = align_up((size_t)n_nodes * sizeof(int));
    size_t offs_b    = align_up((size_t)(n_nodes + 1) * sizeof(int));
    size_t cursor_b  = align_up((size_t)n_nodes * sizeof(int));
    size_t partial_b = align_up(256 * sizeof(int));
    size_t edges_b   = align_up((size_t)n_edges * sizeof(int2));
    size_t need = ping_b + cnt_b + offs_b + cursor_b + partial_b + edges_b;

    if (ws_size < need) {
        // fallback: atomic path (needs only ping buffer)
        float* ws = (float*)d_ws;
        float* dsts[5] = {out, ws, out, ws, out};
        long long total_threads = (long long)n_edges * D_FEAT;
        int block = 256;
        int grid = (int)((total_threads + block - 1) / block);
        const float* src = x;
        for (int s = 0; s < 5; ++s) {
            hipMemsetAsync(dsts[s], 0, buf_bytes, stream);
            spmm_atomic_kernel<<<grid, block, 0, stream>>>(src, vals, rows, cols,
                                                           dsts[s], n_edges);
            src = dsts[s];
        }
        return;
    }

    char* p = (char*)d_ws;
    float* ping   = (float*)p;            p += ping_b;
    int*  cnt     = (int*)p;              p += cnt_b;
    int*  offs    = (int*)p;              p += offs_b;
    int*  cursor  = (int*)p;              p += cursor_b;
    int*  partial = (int*)p;              p += partial_b;
    int2* edges   = (int2*)p;             p += edges_b;

    // ---- build CSR ----
    hipMemsetAsync(cnt, 0, (size_t)n_nodes * sizeof(int), stream);
    {
        int block = 256;
        int grid = (n_edges + block - 1) / block;
        hist_kernel<<<grid, block, 0, stream>>>(rows, cnt, n_edges);
    }
    int nscan_blocks = (n_nodes + 255) / 256;  // 196 for N=50000 (must be <= 256)
    blocksum_kernel<<<nscan_blocks, 256, 0, stream>>>(cnt, partial, n_nodes);
    scan_partials_kernel<<<1, 256, 0, stream>>>(partial, nscan_blocks);
    scan_final_kernel<<<nscan_blocks, 256, 0, stream>>>(cnt, partial, offs, cursor, n_nodes);
    {
        int block = 256;
        int grid = (n_edges + block - 1) / block;
        scatter_kernel<<<grid, block, 0, stream>>>(vals, rows, cols, cursor, edges, n_edges);
    }

    // ---- 5 SpMM steps, ping-pong: x -> out -> ping -> out -> ping -> out ----
    float* dsts[5] = {out, ping, out, ping, out};
    {
        int block = 256;  // 4 waves = 4 rows per block
        int waves_per_block = block / 64;
        int grid = (n_nodes + waves_per_block - 1) / waves_per_block;
        const float* src = x;
        for (int s = 0; s < 5; ++s) {
            spmm_csr_kernel<<<grid, block, 0, stream>>>(src, edges, offs, dsts[s], n_nodes);
            src = dsts[s];
        }
    }
}

// Round 3
// 421.812 us; speedup vs baseline: 3.4506x; 1.3735x over previous
//
#include <hip/hip_runtime.h>

#define D_FEAT 64

// ---------------- CSR build ----------------

__global__ void hist_kernel(const int* __restrict__ rows, int* __restrict__ cnt, int n_edges) {
    int i = blockIdx.x * blockDim.x + threadIdx.x;
    if (i < n_edges) atomicAdd(&cnt[rows[i]], 1);
}

__global__ void blocksum_kernel(const int* __restrict__ cnt, int* __restrict__ partial, int n) {
    __shared__ int buf[256];
    int t = threadIdx.x;
    int i = blockIdx.x * 256 + t;
    buf[t] = (i < n) ? cnt[i] : 0;
    __syncthreads();
    for (int s = 128; s > 0; s >>= 1) {
        if (t < s) buf[t] += buf[t + s];
        __syncthreads();
    }
    if (t == 0) partial[blockIdx.x] = buf[0];
}

__global__ void scan_partials_kernel(int* __restrict__ partial, int nb) {
    __shared__ int buf[256];
    int t = threadIdx.x;
    int v = (t < nb) ? partial[t] : 0;
    buf[t] = v;
    __syncthreads();
    for (int off = 1; off < 256; off <<= 1) {
        int add = (t >= off) ? buf[t - off] : 0;
        __syncthreads();
        buf[t] += add;
        __syncthreads();
    }
    if (t < nb) partial[t] = buf[t] - v;  // exclusive
}

__global__ void scan_final_kernel(const int* __restrict__ cnt, const int* __restrict__ partial,
                                  int* __restrict__ offs, int* __restrict__ cursor, int n) {
    __shared__ int buf[256];
    int t = threadIdx.x;
    int i = blockIdx.x * 256 + t;
    int v = (i < n) ? cnt[i] : 0;
    buf[t] = v;
    __syncthreads();
    for (int off = 1; off < 256; off <<= 1) {
        int add = (t >= off) ? buf[t - off] : 0;
        __syncthreads();
        buf[t] += add;
        __syncthreads();
    }
    int incl = buf[t];
    int base = partial[blockIdx.x];
    if (i < n) {
        offs[i + 1] = base + incl;
        cursor[i] = base + incl - v;
    }
    if (i == 0) offs[0] = 0;
}

__global__ void scatter_kernel(const float* __restrict__ vals, const int* __restrict__ rows,
                               const int* __restrict__ cols, int* __restrict__ cursor,
                               int2* __restrict__ edges, int n_edges) {
    int i = blockIdx.x * blockDim.x + threadIdx.x;
    if (i >= n_edges) return;
    int r = rows[i];
    int pos = atomicAdd(&cursor[r], 1);
    edges[pos] = make_int2(cols[i], __float_as_int(vals[i]));
}

// ---------------- SpMM (no atomics): one wave per row, 8-way gather MLP ----------------

__global__ void spmm_csr_kernel(const float* __restrict__ h,
                                const int2* __restrict__ edges,
                                const int* __restrict__ offs,
                                float* __restrict__ out, int n_nodes) {
    int wid = (int)(((long long)blockIdx.x * blockDim.x + threadIdx.x) >> 6);
    int lane = threadIdx.x & 63;
    if (wid >= n_nodes) return;
    int beg = offs[wid];
    int end = offs[wid + 1];
    float acc = 0.f;
    int j = beg;
    // 8 independent gathers in flight per iteration
    for (; j + 8 <= end; j += 8) {
        int2 e0 = edges[j + 0];
        int2 e1 = edges[j + 1];
        int2 e2 = edges[j + 2];
        int2 e3 = edges[j + 3];
        int2 e4 = edges[j + 4];
        int2 e5 = edges[j + 5];
        int2 e6 = edges[j + 6];
        int2 e7 = edges[j + 7];
        float h0 = h[(size_t)e0.x * D_FEAT + lane];
        float h1 = h[(size_t)e1.x * D_FEAT + lane];
        float h2 = h[(size_t)e2.x * D_FEAT + lane];
        float h3 = h[(size_t)e3.x * D_FEAT + lane];
        float h4 = h[(size_t)e4.x * D_FEAT + lane];
        float h5 = h[(size_t)e5.x * D_FEAT + lane];
        float h6 = h[(size_t)e6.x * D_FEAT + lane];
        float h7 = h[(size_t)e7.x * D_FEAT + lane];
        acc = fmaf(__int_as_float(e0.y), h0, acc);
        acc = fmaf(__int_as_float(e1.y), h1, acc);
        acc = fmaf(__int_as_float(e2.y), h2, acc);
        acc = fmaf(__int_as_float(e3.y), h3, acc);
        acc = fmaf(__int_as_float(e4.y), h4, acc);
        acc = fmaf(__int_as_float(e5.y), h5, acc);
        acc = fmaf(__int_as_float(e6.y), h6, acc);
        acc = fmaf(__int_as_float(e7.y), h7, acc);
    }
    if (j + 4 <= end) {
        int2 e0 = edges[j + 0];
        int2 e1 = edges[j + 1];
        int2 e2 = edges[j + 2];
        int2 e3 = edges[j + 3];
        float h0 = h[(size_t)e0.x * D_FEAT + lane];
        float h1 = h[(size_t)e1.x * D_FEAT + lane];
        float h2 = h[(size_t)e2.x * D_FEAT + lane];
        float h3 = h[(size_t)e3.x * D_FEAT + lane];
        acc = fmaf(__int_as_float(e0.y), h0, acc);
        acc = fmaf(__int_as_float(e1.y), h1, acc);
        acc = fmaf(__int_as_float(e2.y), h2, acc);
        acc = fmaf(__int_as_float(e3.y), h3, acc);
        j += 4;
    }
    for (; j < end; ++j) {
        int2 e = edges[j];
        acc = fmaf(__int_as_float(e.y), h[(size_t)e.x * D_FEAT + lane], acc);
    }
    out[(size_t)wid * D_FEAT + lane] = acc;
}

// ---------------- fallback (atomic path) ----------------

__global__ void spmm_atomic_kernel(const float* __restrict__ h,
                                   const float* __restrict__ vals,
                                   const int* __restrict__ rows,
                                   const int* __restrict__ cols,
                                   float* __restrict__ out,
                                   int n_edges) {
    long long tid = (long long)blockIdx.x * blockDim.x + threadIdx.x;
    int e = (int)(tid >> 6);
    int d = (int)(tid & 63);
    if (e >= n_edges) return;
    float m = vals[e] * h[(size_t)cols[e] * D_FEAT + d];
    atomicAdd(&out[(size_t)rows[e] * D_FEAT + d], m);
}

extern "C" void kernel_launch(void* const* d_in, const int* in_sizes, int n_in,
                              void* d_out, int out_size, void* d_ws, size_t ws_size,
                              hipStream_t stream) {
    const float* x    = (const float*)d_in[0];
    const float* vals = (const float*)d_in[1];
    const int*   rows = (const int*)d_in[2];
    const int*   cols = (const int*)d_in[3];

    int n_nodes = in_sizes[0] / D_FEAT;
    int n_edges = in_sizes[1];

    float* out = (float*)d_out;

    size_t buf_bytes = (size_t)n_nodes * D_FEAT * sizeof(float);

    auto align_up = [](size_t v) { return (v + 255) & ~(size_t)255; };
    size_t ping_b    = align_up(buf_bytes);
    size_t cnt_b     = align_up((size_t)n_nodes * sizeof(int));
    size_t offs_b    = align_up((size_t)(n_nodes + 1) * sizeof(int));
    size_t cursor_b  = align_up((size_t)n_nodes * sizeof(int));
    size_t partial_b = align_up(256 * sizeof(int));
    size_t edges_b   = align_up((size_t)n_edges * sizeof(int2));
    size_t need = ping_b + cnt_b + offs_b + cursor_b + partial_b + edges_b;

    if (ws_size < need) {
        float* ws = (float*)d_ws;
        float* dsts[5] = {out, ws, out, ws, out};
        long long total_threads = (long long)n_edges * D_FEAT;
        int block = 256;
        int grid = (int)((total_threads + block - 1) / block);
        const float* src = x;
        for (int s = 0; s < 5; ++s) {
            hipMemsetAsync(dsts[s], 0, buf_bytes, stream);
            spmm_atomic_kernel<<<grid, block, 0, stream>>>(src, vals, rows, cols,
                                                           dsts[s], n_edges);
            src = dsts[s];
        }
        return;
    }

    char* p = (char*)d_ws;
    float* ping   = (float*)p;            p += ping_b;
    int*  cnt     = (int*)p;              p += cnt_b;
    int*  offs    = (int*)p;              p += offs_b;
    int*  cursor  = (int*)p;              p += cursor_b;
    int*  partial = (int*)p;              p += partial_b;
    int2* edges   = (int2*)p;             p += edges_b;

    // ---- build CSR ----
    hipMemsetAsync(cnt, 0, (size_t)n_nodes * sizeof(int), stream);
    {
        int block = 256;
        int grid = (n_edges + block - 1) / block;
        hist_kernel<<<grid, block, 0, stream>>>(rows, cnt, n_edges);
    }
    int nscan_blocks = (n_nodes + 255) / 256;  // 196 for N=50000 (<= 256)
    blocksum_kernel<<<nscan_blocks, 256, 0, stream>>>(cnt, partial, n_nodes);
    scan_partials_kernel<<<1, 256, 0, stream>>>(partial, nscan_blocks);
    scan_final_kernel<<<nscan_blocks, 256, 0, stream>>>(cnt, partial, offs, cursor, n_nodes);
    {
        int block = 256;
        int grid = (n_edges + block - 1) / block;
        scatter_kernel<<<grid, block, 0, stream>>>(vals, rows, cols, cursor, edges, n_edges);
    }

    // ---- 5 SpMM steps, ping-pong: x -> out -> ping -> out -> ping -> out ----
    float* dsts[5] = {out, ping, out, ping, out};
    {
        int block = 256;  // 4 waves = 4 rows per block
        int waves_per_block = block / 64;
        int grid = (n_nodes + waves_per_block - 1) / waves_per_block;
        const float* src = x;
        for (int s = 0; s < 5; ++s) {
            spmm_csr_kernel<<<grid, block, 0, stream>>>(src, edges, offs, dsts[s], n_nodes);
            src = dsts[s];
        }
    }
}

// Round 4
// 397.217 us; speedup vs baseline: 3.6643x; 1.0619x over previous
//
#include <hip/hip_runtime.h>
#include <hip/hip_fp16.h>
#include <stdint.h>

#define D_FEAT 64

// ---------------- CSR build ----------------

__global__ void hist_kernel(const int* __restrict__ rows, int* __restrict__ cnt, int n_edges) {
    int i = blockIdx.x * blockDim.x + threadIdx.x;
    if (i < n_edges) atomicAdd(&cnt[rows[i]], 1);
}

__global__ void blocksum_kernel(const int* __restrict__ cnt, int* __restrict__ partial, int n) {
    __shared__ int buf[256];
    int t = threadIdx.x;
    int i = blockIdx.x * 256 + t;
    buf[t] = (i < n) ? cnt[i] : 0;
    __syncthreads();
    for (int s = 128; s > 0; s >>= 1) {
        if (t < s) buf[t] += buf[t + s];
        __syncthreads();
    }
    if (t == 0) partial[blockIdx.x] = buf[0];
}

__global__ void scan_partials_kernel(int* __restrict__ partial, int nb) {
    __shared__ int buf[256];
    int t = threadIdx.x;
    int v = (t < nb) ? partial[t] : 0;
    buf[t] = v;
    __syncthreads();
    for (int off = 1; off < 256; off <<= 1) {
        int add = (t >= off) ? buf[t - off] : 0;
        __syncthreads();
        buf[t] += add;
        __syncthreads();
    }
    if (t < nb) partial[t] = buf[t] - v;  // exclusive
}

__global__ void scan_final_kernel(const int* __restrict__ cnt, const int* __restrict__ partial,
                                  int* __restrict__ offs, int* __restrict__ cursor, int n) {
    __shared__ int buf[256];
    int t = threadIdx.x;
    int i = blockIdx.x * 256 + t;
    int v = (i < n) ? cnt[i] : 0;
    buf[t] = v;
    __syncthreads();
    for (int off = 1; off < 256; off <<= 1) {
        int add = (t >= off) ? buf[t - off] : 0;
        __syncthreads();
        buf[t] += add;
        __syncthreads();
    }
    int incl = buf[t];
    int base = partial[blockIdx.x];
    if (i < n) {
        offs[i + 1] = base + incl;
        cursor[i] = base + incl - v;
    }
    if (i == 0) offs[0] = 0;
}

// Scatter edges into row-sorted packed records: (col:16 bits) | (half(val) << 16)
__global__ void scatter_pack_kernel(const float* __restrict__ vals, const int* __restrict__ rows,
                                    const int* __restrict__ cols, int* __restrict__ cursor,
                                    uint32_t* __restrict__ edges, int n_edges) {
    int i = blockIdx.x * blockDim.x + threadIdx.x;
    if (i >= n_edges) return;
    int r = rows[i];
    int pos = atomicAdd(&cursor[r], 1);
    __half hv = __float2half_rn(vals[i]);
    unsigned short vb = *reinterpret_cast<unsigned short*>(&hv);
    edges[pos] = (uint32_t)(cols[i] & 0xFFFF) | ((uint32_t)vb << 16);
}

// ---------------- SpMM: one wave per row, packed 4B edges, fp16 intermediates ----------------

__device__ __forceinline__ float unpack_val(uint32_t u) {
    __half_raw hr;
    hr.x = (unsigned short)(u >> 16);
    return __half2float(__half(hr));
}

template <bool IN_F32, bool OUT_F32>
__global__ __launch_bounds__(256) void spmm_pk_kernel(const void* __restrict__ hv,
                                                      const uint32_t* __restrict__ edges,
                                                      const int* __restrict__ offs,
                                                      void* __restrict__ outv, int n_nodes) {
    const float* hf = (const float*)hv;
    const __half* hh = (const __half*)hv;
    float* outf = (float*)outv;
    __half* outh = (__half*)outv;

    int wid = (int)(((long long)blockIdx.x * blockDim.x + threadIdx.x) >> 6);
    int lane = threadIdx.x & 63;
    if (wid >= n_nodes) return;
    int beg = offs[wid];
    int end = offs[wid + 1];
    float acc = 0.f;
    int j = beg;

#define GATHER(u) (IN_F32 ? hf[(size_t)((u) & 0xFFFF) * D_FEAT + lane] \
                          : __half2float(hh[(size_t)((u) & 0xFFFF) * D_FEAT + lane]))

    for (; j + 8 <= end; j += 8) {
        uint32_t u0 = edges[j + 0];
        uint32_t u1 = edges[j + 1];
        uint32_t u2 = edges[j + 2];
        uint32_t u3 = edges[j + 3];
        uint32_t u4 = edges[j + 4];
        uint32_t u5 = edges[j + 5];
        uint32_t u6 = edges[j + 6];
        uint32_t u7 = edges[j + 7];
        float h0 = GATHER(u0);
        float h1 = GATHER(u1);
        float h2 = GATHER(u2);
        float h3 = GATHER(u3);
        float h4 = GATHER(u4);
        float h5 = GATHER(u5);
        float h6 = GATHER(u6);
        float h7 = GATHER(u7);
        acc = fmaf(unpack_val(u0), h0, acc);
        acc = fmaf(unpack_val(u1), h1, acc);
        acc = fmaf(unpack_val(u2), h2, acc);
        acc = fmaf(unpack_val(u3), h3, acc);
        acc = fmaf(unpack_val(u4), h4, acc);
        acc = fmaf(unpack_val(u5), h5, acc);
        acc = fmaf(unpack_val(u6), h6, acc);
        acc = fmaf(unpack_val(u7), h7, acc);
    }
    if (j + 4 <= end) {
        uint32_t u0 = edges[j + 0];
        uint32_t u1 = edges[j + 1];
        uint32_t u2 = edges[j + 2];
        uint32_t u3 = edges[j + 3];
        float h0 = GATHER(u0);
        float h1 = GATHER(u1);
        float h2 = GATHER(u2);
        float h3 = GATHER(u3);
        acc = fmaf(unpack_val(u0), h0, acc);
        acc = fmaf(unpack_val(u1), h1, acc);
        acc = fmaf(unpack_val(u2), h2, acc);
        acc = fmaf(unpack_val(u3), h3, acc);
        j += 4;
    }
    for (; j < end; ++j) {
        uint32_t u = edges[j];
        acc = fmaf(unpack_val(u), GATHER(u), acc);
    }
#undef GATHER

    if (OUT_F32) {
        outf[(size_t)wid * D_FEAT + lane] = acc;
    } else {
        outh[(size_t)wid * D_FEAT + lane] = __float2half_rn(acc);
    }
}

// ---------------- fallback (atomic path, used only if n_nodes > 65536 or tiny ws) ----------------

__global__ void spmm_atomic_kernel(const float* __restrict__ h,
                                   const float* __restrict__ vals,
                                   const int* __restrict__ rows,
                                   const int* __restrict__ cols,
                                   float* __restrict__ out,
                                   int n_edges) {
    long long tid = (long long)blockIdx.x * blockDim.x + threadIdx.x;
    int e = (int)(tid >> 6);
    int d = (int)(tid & 63);
    if (e >= n_edges) return;
    float m = vals[e] * h[(size_t)cols[e] * D_FEAT + d];
    atomicAdd(&out[(size_t)rows[e] * D_FEAT + d], m);
}

extern "C" void kernel_launch(void* const* d_in, const int* in_sizes, int n_in,
                              void* d_out, int out_size, void* d_ws, size_t ws_size,
                              hipStream_t stream) {
    const float* x    = (const float*)d_in[0];
    const float* vals = (const float*)d_in[1];
    const int*   rows = (const int*)d_in[2];
    const int*   cols = (const int*)d_in[3];

    int n_nodes = in_sizes[0] / D_FEAT;
    int n_edges = in_sizes[1];

    float* out = (float*)d_out;

    size_t buf_bytes_f32 = (size_t)n_nodes * D_FEAT * sizeof(float);
    size_t buf_bytes_f16 = (size_t)n_nodes * D_FEAT * sizeof(__half);

    auto align_up = [](size_t v) { return (v + 255) & ~(size_t)255; };
    size_t pa_b      = align_up(buf_bytes_f16);
    size_t pb_b      = align_up(buf_bytes_f16);
    size_t cnt_b     = align_up((size_t)n_nodes * sizeof(int));
    size_t offs_b    = align_up((size_t)(n_nodes + 1) * sizeof(int));
    size_t cursor_b  = align_up((size_t)n_nodes * sizeof(int));
    size_t partial_b = align_up(256 * sizeof(int));
    size_t edges_b   = align_up((size_t)n_edges * sizeof(uint32_t));
    size_t need = pa_b + pb_b + cnt_b + offs_b + cursor_b + partial_b + edges_b;

    int nscan_blocks = (n_nodes + 255) / 256;

    if (ws_size < need || n_nodes > 65536 || nscan_blocks > 256) {
        // fallback: atomic path (needs only one f32 ping buffer)
        float* ws = (float*)d_ws;
        float* dsts[5] = {out, ws, out, ws, out};
        long long total_threads = (long long)n_edges * D_FEAT;
        int block = 256;
        int grid = (int)((total_threads + block - 1) / block);
        const float* src = x;
        for (int s = 0; s < 5; ++s) {
            hipMemsetAsync(dsts[s], 0, buf_bytes_f32, stream);
            spmm_atomic_kernel<<<grid, block, 0, stream>>>(src, vals, rows, cols,
                                                           dsts[s], n_edges);
            src = dsts[s];
        }
        return;
    }

    char* p = (char*)d_ws;
    __half*   pA      = (__half*)p;     p += pa_b;
    __half*   pB      = (__half*)p;     p += pb_b;
    int*      cnt     = (int*)p;        p += cnt_b;
    int*      offs    = (int*)p;        p += offs_b;
    int*      cursor  = (int*)p;        p += cursor_b;
    int*      partial = (int*)p;        p += partial_b;
    uint32_t* edges   = (uint32_t*)p;   p += edges_b;

    // ---- build CSR (packed records) ----
    hipMemsetAsync(cnt, 0, (size_t)n_nodes * sizeof(int), stream);
    {
        int block = 256;
        int grid = (n_edges + block - 1) / block;
        hist_kernel<<<grid, block, 0, stream>>>(rows, cnt, n_edges);
    }
    blocksum_kernel<<<nscan_blocks, 256, 0, stream>>>(cnt, partial, n_nodes);
    scan_partials_kernel<<<1, 256, 0, stream>>>(partial, nscan_blocks);
    scan_final_kernel<<<nscan_blocks, 256, 0, stream>>>(cnt, partial, offs, cursor, n_nodes);
    {
        int block = 256;
        int grid = (n_edges + block - 1) / block;
        scatter_pack_kernel<<<grid, block, 0, stream>>>(vals, rows, cols, cursor, edges, n_edges);
    }

    // ---- 5 SpMM steps: x(f32) -> pA(f16) -> pB -> pA -> pB -> out(f32) ----
    {
        int block = 256;  // 4 waves = 4 rows per block
        int waves_per_block = block / 64;
        int grid = (n_nodes + waves_per_block - 1) / waves_per_block;

        spmm_pk_kernel<true, false><<<grid, block, 0, stream>>>(x, edges, offs, pA, n_nodes);
        spmm_pk_kernel<false, false><<<grid, block, 0, stream>>>(pA, edges, offs, pB, n_nodes);
        spmm_pk_kernel<false, false><<<grid, block, 0, stream>>>(pB, edges, offs, pA, n_nodes);
        spmm_pk_kernel<false, false><<<grid, block, 0, stream>>>(pA, edges, offs, pB, n_nodes);
        spmm_pk_kernel<false, true><<<grid, block, 0, stream>>>(pB, edges, offs, out, n_nodes);
    }
}

// Round 5
// 320.607 us; speedup vs baseline: 4.5399x; 1.2390x over previous
//
#include <hip/hip_runtime.h>
#include <hip/hip_fp16.h>
#include <stdint.h>

#define D_FEAT 64
#define CH 16384        // edges per chunk in hist/place
#define BKT_BITS 8      // 256 rows per bucket

// ---------------- bucket histogram per chunk ----------------
__global__ __launch_bounds__(256) void bhist_kernel(const int* __restrict__ rows,
                                                    int* __restrict__ block_hist,
                                                    int n_edges, int nb) {
    __shared__ int cnt[256];
    cnt[threadIdx.x] = 0;
    __syncthreads();
    int beg = blockIdx.x * CH;
    int end = min(beg + CH, n_edges);
    for (int i = beg + threadIdx.x; i < end; i += 256)
        atomicAdd(&cnt[rows[i] >> BKT_BITS], 1);
    __syncthreads();
    if (threadIdx.x < nb)
        block_hist[blockIdx.x * nb + threadIdx.x] = cnt[threadIdx.x];
}

// ---------------- per-bucket column scan + bucket base scan (1 block) ----------------
__global__ __launch_bounds__(256) void bscan_kernel(int* __restrict__ block_hist,
                                                    int* __restrict__ bbase,
                                                    int nchunks, int nb) {
    __shared__ int buf[256];
    int j = threadIdx.x;
    int running = 0;
    if (j < nb) {
        for (int b = 0; b < nchunks; ++b) {
            int v = block_hist[b * nb + j];
            block_hist[b * nb + j] = running;   // exclusive within-bucket base for chunk b
            running += v;
        }
    }
    int v = running;                             // bucket total
    buf[j] = v;
    __syncthreads();
    for (int off = 1; off < 256; off <<= 1) {
        int add = (j >= off) ? buf[j - off] : 0;
        __syncthreads();
        buf[j] += add;
        __syncthreads();
    }
    int excl = buf[j] - v;
    if (j < nb) {
        bbase[j] = excl;
        if (j == nb - 1) bbase[nb] = excl + v;   // = n_edges
    }
}

// ---------------- place edges into bucket-contiguous mid array ----------------
__global__ __launch_bounds__(256) void bplace_kernel(const float* __restrict__ vals,
                                                     const int* __restrict__ rows,
                                                     const int* __restrict__ cols,
                                                     const int* __restrict__ block_hist,
                                                     const int* __restrict__ bbase,
                                                     uint2* __restrict__ mid,
                                                     int n_edges, int nb) {
    __shared__ int cnt[256];
    __shared__ int base[256];
    int t = threadIdx.x;
    cnt[t] = 0;
    if (t < nb) base[t] = bbase[t] + block_hist[blockIdx.x * nb + t];
    __syncthreads();
    int beg = blockIdx.x * CH;
    int end = min(beg + CH, n_edges);
    for (int i = beg + t; i < end; i += 256) {
        int r = rows[i];
        int b = r >> BKT_BITS;
        int lrank = atomicAdd(&cnt[b], 1);
        __half hv = __float2half_rn(vals[i]);
        unsigned short vb = *reinterpret_cast<unsigned short*>(&hv);
        uint32_t packed = (uint32_t)(cols[i] & 0xFFFF) | ((uint32_t)vb << 16);
        mid[base[b] + lrank] = make_uint2(packed, (uint32_t)r);
    }
}

// ---------------- per-bucket counting sort by row + fused offs[] ----------------
__global__ __launch_bounds__(256) void bsort_kernel(uint2* __restrict__ mid,
                                                    const int* __restrict__ bbase,
                                                    uint32_t* __restrict__ edges,
                                                    int* __restrict__ offs,
                                                    int n_nodes, int nb) {
    __shared__ int cnt[256];
    __shared__ int buf[256];
    int j = blockIdx.x;
    int t = threadIdx.x;
    int lo = bbase[j];
    int hi = bbase[j + 1];
    cnt[t] = 0;
    __syncthreads();
    const uint32_t RMASK = (1u << BKT_BITS) - 1u;
    // pass 1: assign per-row rank, stash rank in high 16 bits of mid[i].y
    for (int i = lo + t; i < hi; i += 256) {
        uint2 e = mid[i];
        int r = (int)(e.y & RMASK);
        int rank = atomicAdd(&cnt[r], 1);
        mid[i].y = e.y | ((uint32_t)rank << 16);
    }
    __syncthreads();
    // exclusive scan of per-row counts
    int v = cnt[t];
    buf[t] = v;
    __syncthreads();
    for (int off = 1; off < 256; off <<= 1) {
        int add = (t >= off) ? buf[t - off] : 0;
        __syncthreads();
        buf[t] += add;
        __syncthreads();
    }
    int start = buf[t] - v;  // exclusive prefix within bucket
    int rg = (j << BKT_BITS) + t;
    if (rg <= n_nodes) offs[rg] = lo + start;
    __syncthreads();
    cnt[t] = start;
    __syncthreads();
    // pass 2: each thread re-reads its OWN mid entries (same stride pattern)
    for (int i = lo + t; i < hi; i += 256) {
        uint2 e = mid[i];
        int r = (int)(e.y & RMASK);
        int rank = (int)(e.y >> 16);
        edges[lo + cnt[r] + rank] = e.x;
    }
}

// ---------------- SpMM: one wave per row, packed 4B edges, fp16 intermediates ----------------

__device__ __forceinline__ float unpack_val(uint32_t u) {
    __half_raw hr;
    hr.x = (unsigned short)(u >> 16);
    return __half2float(__half(hr));
}

template <bool IN_F32>
__device__ __forceinline__ float gather_one(const void* hv, uint32_t u, int lane) {
    if (IN_F32) return ((const float*)hv)[(size_t)(u & 0xFFFF) * D_FEAT + lane];
    return __half2float(((const __half*)hv)[(size_t)(u & 0xFFFF) * D_FEAT + lane]);
}

template <int K, bool IN_F32>
__device__ __forceinline__ void gfma(const void* hv, const uint32_t* __restrict__ edges,
                                     int j, int lane, float& acc) {
    uint32_t u[K];
#pragma unroll
    for (int k = 0; k < K; ++k) u[k] = edges[j + k];
    float hh[K];
#pragma unroll
    for (int k = 0; k < K; ++k) hh[k] = gather_one<IN_F32>(hv, u[k], lane);
#pragma unroll
    for (int k = 0; k < K; ++k) acc = fmaf(unpack_val(u[k]), hh[k], acc);
}

template <bool IN_F32, bool OUT_F32>
__global__ __launch_bounds__(256) void spmm_pk_kernel(const void* __restrict__ hv,
                                                      const uint32_t* __restrict__ edges,
                                                      const int* __restrict__ offs,
                                                      void* __restrict__ outv, int n_nodes) {
    int wid = (int)(((long long)blockIdx.x * blockDim.x + threadIdx.x) >> 6);
    int lane = threadIdx.x & 63;
    if (wid >= n_nodes) return;
    int beg = offs[wid];
    int end = offs[wid + 1];
    float acc = 0.f;
    int j = beg;
    for (; j + 16 <= end; j += 16) gfma<16, IN_F32>(hv, edges, j, lane, acc);
    if (j + 8 <= end) { gfma<8, IN_F32>(hv, edges, j, lane, acc); j += 8; }
    if (j + 4 <= end) { gfma<4, IN_F32>(hv, edges, j, lane, acc); j += 4; }
    for (; j < end; ++j) {
        uint32_t u = edges[j];
        acc = fmaf(unpack_val(u), gather_one<IN_F32>(hv, u, lane), acc);
    }
    if (OUT_F32) ((float*)outv)[(size_t)wid * D_FEAT + lane] = acc;
    else ((__half*)outv)[(size_t)wid * D_FEAT + lane] = __float2half_rn(acc);
}

// ---------------- fallback (atomic path) ----------------

__global__ void spmm_atomic_kernel(const float* __restrict__ h,
                                   const float* __restrict__ vals,
                                   const int* __restrict__ rows,
                                   const int* __restrict__ cols,
                                   float* __restrict__ out,
                                   int n_edges) {
    long long tid = (long long)blockIdx.x * blockDim.x + threadIdx.x;
    int e = (int)(tid >> 6);
    int d = (int)(tid & 63);
    if (e >= n_edges) return;
    float m = vals[e] * h[(size_t)cols[e] * D_FEAT + d];
    atomicAdd(&out[(size_t)rows[e] * D_FEAT + d], m);
}

extern "C" void kernel_launch(void* const* d_in, const int* in_sizes, int n_in,
                              void* d_out, int out_size, void* d_ws, size_t ws_size,
                              hipStream_t stream) {
    const float* x    = (const float*)d_in[0];
    const float* vals = (const float*)d_in[1];
    const int*   rows = (const int*)d_in[2];
    const int*   cols = (const int*)d_in[3];

    int n_nodes = in_sizes[0] / D_FEAT;
    int n_edges = in_sizes[1];

    float* out = (float*)d_out;

    size_t buf_bytes_f32 = (size_t)n_nodes * D_FEAT * sizeof(float);
    size_t buf_bytes_f16 = (size_t)n_nodes * D_FEAT * sizeof(__half);

    auto align_up = [](size_t v) { return (v + 255) & ~(size_t)255; };

    int nb = (n_nodes + 255) >> BKT_BITS;          // buckets (<= 256 when n <= 65536)
    int nchunks = (n_edges + CH - 1) / CH;

    size_t pa_b   = align_up(buf_bytes_f16);
    size_t pb_b   = align_up(buf_bytes_f16);
    size_t mid_b  = align_up((size_t)n_edges * sizeof(uint2));
    size_t region1 = pa_b + pb_b;
    if (mid_b > region1) region1 = mid_b;          // mid aliases pA/pB (dead before spmm)
    size_t edges_b = align_up((size_t)n_edges * sizeof(uint32_t));
    size_t offs_b  = align_up((size_t)(n_nodes + 1) * sizeof(int));
    size_t bh_b    = align_up((size_t)nchunks * nb * sizeof(int));
    size_t bb_b    = align_up((size_t)(nb + 1) * sizeof(int));
    size_t need = region1 + edges_b + offs_b + bh_b + bb_b;

    if (ws_size < need || n_nodes > 65536) {
        // fallback: atomic path (needs only one f32 ping buffer)
        float* ws = (float*)d_ws;
        float* dsts[5] = {out, ws, out, ws, out};
        long long total_threads = (long long)n_edges * D_FEAT;
        int block = 256;
        int grid = (int)((total_threads + block - 1) / block);
        const float* src = x;
        for (int s = 0; s < 5; ++s) {
            hipMemsetAsync(dsts[s], 0, buf_bytes_f32, stream);
            spmm_atomic_kernel<<<grid, block, 0, stream>>>(src, vals, rows, cols,
                                                           dsts[s], n_edges);
            src = dsts[s];
        }
        return;
    }

    char* p = (char*)d_ws;
    char* r1 = p;                        p += region1;
    uint32_t* edges      = (uint32_t*)p; p += edges_b;
    int*      offs       = (int*)p;      p += offs_b;
    int*      block_hist = (int*)p;      p += bh_b;
    int*      bbase      = (int*)p;      p += bb_b;

    __half* pA = (__half*)r1;
    __half* pB = (__half*)(r1 + pa_b);
    uint2*  mid = (uint2*)r1;            // aliases pA/pB; consumed before they're written

    // ---- build row-sorted packed edge list + offs ----
    bhist_kernel<<<nchunks, 256, 0, stream>>>(rows, block_hist, n_edges, nb);
    bscan_kernel<<<1, 256, 0, stream>>>(block_hist, bbase, nchunks, nb);
    bplace_kernel<<<nchunks, 256, 0, stream>>>(vals, rows, cols, block_hist, bbase,
                                               mid, n_edges, nb);
    bsort_kernel<<<nb, 256, 0, stream>>>(mid, bbase, edges, offs, n_nodes, nb);

    // ---- 5 SpMM steps: x(f32) -> pA(f16) -> pB -> pA -> pB -> out(f32) ----
    {
        int waves_per_block = 4;  // 256 threads
        int grid = (n_nodes + waves_per_block - 1) / waves_per_block;
        spmm_pk_kernel<true,  false><<<grid, 256, 0, stream>>>(x,  edges, offs, pA, n_nodes);
        spmm_pk_kernel<false, false><<<grid, 256, 0, stream>>>(pA, edges, offs, pB, n_nodes);
        spmm_pk_kernel<false, false><<<grid, 256, 0, stream>>>(pB, edges, offs, pA, n_nodes);
        spmm_pk_kernel<false, false><<<grid, 256, 0, stream>>>(pA, edges, offs, pB, n_nodes);
        spmm_pk_kernel<false, true ><<<grid, 256, 0, stream>>>(pB, edges, offs, out, n_nodes);
    }
}

// Round 6
// 244.130 us; speedup vs baseline: 5.9621x; 1.3133x over previous
//
#include <hip/hip_runtime.h>
#include <hip/hip_fp16.h>
#include <stdint.h>

#define D_FEAT 64
#define CH 4096         // edges per chunk in hist/place (306 chunks @ 1.25M edges)
#define BKT_BITS 8      // 256 rows per bucket

// ---------------- bucket histogram per chunk ----------------
__global__ __launch_bounds__(256) void bhist_kernel(const int* __restrict__ rows,
                                                    int* __restrict__ block_hist,
                                                    int n_edges, int nb) {
    __shared__ int cnt[256];
    cnt[threadIdx.x] = 0;
    __syncthreads();
    int beg = blockIdx.x * CH;
    int end = min(beg + CH, n_edges);
    for (int i = beg + threadIdx.x; i < end; i += 256)
        atomicAdd(&cnt[rows[i] >> BKT_BITS], 1);
    __syncthreads();
    if (threadIdx.x < nb)
        block_hist[blockIdx.x * nb + threadIdx.x] = cnt[threadIdx.x];
}

// ---------------- parallel scan: per-bucket column over chunks (nchunks <= 512) ----------------
__global__ __launch_bounds__(256) void bscan1_kernel(int* __restrict__ block_hist,
                                                     int* __restrict__ btot,
                                                     int nchunks, int nb) {
    __shared__ int buf[256];
    int j = blockIdx.x;
    int t = threadIdx.x;
    int c0 = 2 * t, c1 = 2 * t + 1;
    int v0 = (c0 < nchunks) ? block_hist[(size_t)c0 * nb + j] : 0;
    int v1 = (c1 < nchunks) ? block_hist[(size_t)c1 * nb + j] : 0;
    int loc = v0 + v1;
    buf[t] = loc;
    __syncthreads();
    for (int off = 1; off < 256; off <<= 1) {
        int add = (t >= off) ? buf[t - off] : 0;
        __syncthreads();
        buf[t] += add;
        __syncthreads();
    }
    int excl = buf[t] - loc;
    if (c0 < nchunks) block_hist[(size_t)c0 * nb + j] = excl;
    if (c1 < nchunks) block_hist[(size_t)c1 * nb + j] = excl + v0;
    if (t == 255) btot[j] = buf[255];
}

// exclusive scan of bucket totals (1 block, nb <= 256)
__global__ __launch_bounds__(256) void bscan2_kernel(const int* __restrict__ btot,
                                                     int* __restrict__ bbase, int nb) {
    __shared__ int buf[256];
    int t = threadIdx.x;
    int v = (t < nb) ? btot[t] : 0;
    buf[t] = v;
    __syncthreads();
    for (int off = 1; off < 256; off <<= 1) {
        int add = (t >= off) ? buf[t - off] : 0;
        __syncthreads();
        buf[t] += add;
        __syncthreads();
    }
    if (t < nb) {
        bbase[t] = buf[t] - v;
        if (t == nb - 1) bbase[nb] = buf[t];
    }
}

// ---------------- place edges into bucket-contiguous mid array ----------------
__global__ __launch_bounds__(256) void bplace_kernel(const float* __restrict__ vals,
                                                     const int* __restrict__ rows,
                                                     const int* __restrict__ cols,
                                                     const int* __restrict__ block_hist,
                                                     const int* __restrict__ bbase,
                                                     uint2* __restrict__ mid,
                                                     int n_edges, int nb) {
    __shared__ int cnt[256];
    __shared__ int base[256];
    int t = threadIdx.x;
    cnt[t] = 0;
    if (t < nb) base[t] = bbase[t] + block_hist[(size_t)blockIdx.x * nb + t];
    __syncthreads();
    int beg = blockIdx.x * CH;
    int end = min(beg + CH, n_edges);
    for (int i = beg + t; i < end; i += 256) {
        int r = rows[i];
        int b = r >> BKT_BITS;
        int lrank = atomicAdd(&cnt[b], 1);
        __half hv = __float2half_rn(vals[i]);
        unsigned short vb = *reinterpret_cast<unsigned short*>(&hv);
        uint32_t packed = (uint32_t)(cols[i] & 0xFFFF) | ((uint32_t)vb << 16);
        mid[base[b] + lrank] = make_uint2(packed, (uint32_t)r);
    }
}

// ---------------- per-bucket counting sort by row + fused offs[] ----------------
__global__ __launch_bounds__(256) void bsort_kernel(uint2* __restrict__ mid,
                                                    const int* __restrict__ bbase,
                                                    uint32_t* __restrict__ edges,
                                                    int* __restrict__ offs,
                                                    int n_nodes, int nb) {
    __shared__ int cnt[256];
    __shared__ int buf[256];
    int j = blockIdx.x;
    int t = threadIdx.x;
    int lo = bbase[j];
    int hi = bbase[j + 1];
    cnt[t] = 0;
    __syncthreads();
    const uint32_t RMASK = (1u << BKT_BITS) - 1u;
    for (int i = lo + t; i < hi; i += 256) {
        uint2 e = mid[i];
        int r = (int)(e.y & RMASK);
        int rank = atomicAdd(&cnt[r], 1);
        mid[i].y = e.y | ((uint32_t)rank << 16);
    }
    __syncthreads();
    int v = cnt[t];
    buf[t] = v;
    __syncthreads();
    for (int off = 1; off < 256; off <<= 1) {
        int add = (t >= off) ? buf[t - off] : 0;
        __syncthreads();
        buf[t] += add;
        __syncthreads();
    }
    int start = buf[t] - v;
    int rg = (j << BKT_BITS) + t;
    if (rg <= n_nodes) offs[rg] = lo + start;
    __syncthreads();
    cnt[t] = start;
    __syncthreads();
    for (int i = lo + t; i < hi; i += 256) {
        uint2 e = mid[i];
        int r = (int)(e.y & RMASK);
        int rank = (int)(e.y >> 16);
        edges[lo + cnt[r] + rank] = e.x;
    }
}

// ---------------- SpMM: 2 rows per wave (32 lanes each), float2 features ----------------

__device__ __forceinline__ float unpack_val(uint32_t u) {
    __half_raw hr;
    hr.x = (unsigned short)(u >> 16);
    return __half2float(__half(hr));
}

template <int K, bool IN_F32>
__device__ __forceinline__ void gfma2(const void* __restrict__ hv,
                                      const uint32_t* __restrict__ edges,
                                      int j, int gl, float2& acc) {
    uint32_t u[K];
#pragma unroll
    for (int k = 0; k < K; ++k) u[k] = edges[j + k];
    float2 hh[K];
#pragma unroll
    for (int k = 0; k < K; ++k) {
        size_t c = (size_t)(u[k] & 0xFFFF);
        if (IN_F32) hh[k] = ((const float2*)hv)[c * 32 + gl];
        else        hh[k] = __half22float2(((const __half2*)hv)[c * 32 + gl]);
    }
#pragma unroll
    for (int k = 0; k < K; ++k) {
        float v = unpack_val(u[k]);
        acc.x = fmaf(v, hh[k].x, acc.x);
        acc.y = fmaf(v, hh[k].y, acc.y);
    }
}

template <bool IN_F32, bool OUT_F32>
__global__ __launch_bounds__(256) void spmm2_kernel(const void* __restrict__ hv,
                                                    const uint32_t* __restrict__ edges,
                                                    const int* __restrict__ offs,
                                                    void* __restrict__ outv, int n_nodes) {
    int wave = (int)(((long long)blockIdx.x * blockDim.x + threadIdx.x) >> 6);
    int lane = threadIdx.x & 63;
    int g = lane >> 5;       // which row of the pair
    int gl = lane & 31;      // lane within 32-lane group; features (2gl, 2gl+1)
    int row = wave * 2 + g;
    if (row >= n_nodes) return;
    int beg = offs[row];
    int end = offs[row + 1];
    float2 acc = make_float2(0.f, 0.f);
    int j = beg;
    for (; j + 8 <= end; j += 8) gfma2<8, IN_F32>(hv, edges, j, gl, acc);
    if (j + 4 <= end) { gfma2<4, IN_F32>(hv, edges, j, gl, acc); j += 4; }
    for (; j < end; ++j) {
        uint32_t u = edges[j];
        size_t c = (size_t)(u & 0xFFFF);
        float2 hh = IN_F32 ? ((const float2*)hv)[c * 32 + gl]
                           : __half22float2(((const __half2*)hv)[c * 32 + gl]);
        float v = unpack_val(u);
        acc.x = fmaf(v, hh.x, acc.x);
        acc.y = fmaf(v, hh.y, acc.y);
    }
    if (OUT_F32) {
        ((float2*)outv)[(size_t)row * 32 + gl] = acc;
    } else {
        ((__half2*)outv)[(size_t)row * 32 + gl] = __float22half2_rn(acc);
    }
}

// ---------------- fallback (atomic path) ----------------

__global__ void spmm_atomic_kernel(const float* __restrict__ h,
                                   const float* __restrict__ vals,
                                   const int* __restrict__ rows,
                                   const int* __restrict__ cols,
                                   float* __restrict__ out,
                                   int n_edges) {
    long long tid = (long long)blockIdx.x * blockDim.x + threadIdx.x;
    int e = (int)(tid >> 6);
    int d = (int)(tid & 63);
    if (e >= n_edges) return;
    float m = vals[e] * h[(size_t)cols[e] * D_FEAT + d];
    atomicAdd(&out[(size_t)rows[e] * D_FEAT + d], m);
}

extern "C" void kernel_launch(void* const* d_in, const int* in_sizes, int n_in,
                              void* d_out, int out_size, void* d_ws, size_t ws_size,
                              hipStream_t stream) {
    const float* x    = (const float*)d_in[0];
    const float* vals = (const float*)d_in[1];
    const int*   rows = (const int*)d_in[2];
    const int*   cols = (const int*)d_in[3];

    int n_nodes = in_sizes[0] / D_FEAT;
    int n_edges = in_sizes[1];

    float* out = (float*)d_out;

    size_t buf_bytes_f32 = (size_t)n_nodes * D_FEAT * sizeof(float);
    size_t buf_bytes_f16 = (size_t)n_nodes * D_FEAT * sizeof(__half);

    auto align_up = [](size_t v) { return (v + 255) & ~(size_t)255; };

    int nb = (n_nodes + 255) >> BKT_BITS;          // buckets (<= 256 when n <= 65536)
    int nchunks = (n_edges + CH - 1) / CH;

    size_t pa_b   = align_up(buf_bytes_f16);
    size_t pb_b   = align_up(buf_bytes_f16);
    size_t mid_b  = align_up((size_t)n_edges * sizeof(uint2));
    size_t region1 = pa_b + pb_b;
    if (mid_b > region1) region1 = mid_b;          // mid aliases pA/pB (dead before spmm)
    size_t edges_b = align_up((size_t)n_edges * sizeof(uint32_t));
    size_t offs_b  = align_up((size_t)(n_nodes + 1) * sizeof(int));
    size_t bh_b    = align_up((size_t)nchunks * nb * sizeof(int));
    size_t bb_b    = align_up((size_t)(nb + 1) * sizeof(int));
    size_t bt_b    = align_up(256 * sizeof(int));
    size_t need = region1 + edges_b + offs_b + bh_b + bb_b + bt_b;

    if (ws_size < need || n_nodes > 65536 || nchunks > 512) {
        // fallback: atomic path (needs only one f32 ping buffer)
        float* ws = (float*)d_ws;
        float* dsts[5] = {out, ws, out, ws, out};
        long long total_threads = (long long)n_edges * D_FEAT;
        int block = 256;
        int grid = (int)((total_threads + block - 1) / block);
        const float* src = x;
        for (int s = 0; s < 5; ++s) {
            hipMemsetAsync(dsts[s], 0, buf_bytes_f32, stream);
            spmm_atomic_kernel<<<grid, block, 0, stream>>>(src, vals, rows, cols,
                                                           dsts[s], n_edges);
            src = dsts[s];
        }
        return;
    }

    char* p = (char*)d_ws;
    char* r1 = p;                        p += region1;
    uint32_t* edges      = (uint32_t*)p; p += edges_b;
    int*      offs       = (int*)p;      p += offs_b;
    int*      block_hist = (int*)p;      p += bh_b;
    int*      bbase      = (int*)p;      p += bb_b;
    int*      btot       = (int*)p;      p += bt_b;

    __half* pA = (__half*)r1;
    __half* pB = (__half*)(r1 + pa_b);
    uint2*  mid = (uint2*)r1;            // aliases pA/pB; consumed before they're written

    // ---- build row-sorted packed edge list + offs ----
    bhist_kernel<<<nchunks, 256, 0, stream>>>(rows, block_hist, n_edges, nb);
    bscan1_kernel<<<nb, 256, 0, stream>>>(block_hist, btot, nchunks, nb);
    bscan2_kernel<<<1, 256, 0, stream>>>(btot, bbase, nb);
    bplace_kernel<<<nchunks, 256, 0, stream>>>(vals, rows, cols, block_hist, bbase,
                                               mid, n_edges, nb);
    bsort_kernel<<<nb, 256, 0, stream>>>(mid, bbase, edges, offs, n_nodes, nb);

    // ---- 5 SpMM steps: x(f32) -> pA(f16) -> pB -> pA -> pB -> out(f32) ----
    {
        int rows_per_block = 8;  // 4 waves x 2 rows
        int grid = (n_nodes + rows_per_block - 1) / rows_per_block;
        spmm2_kernel<true,  false><<<grid, 256, 0, stream>>>(x,  edges, offs, pA, n_nodes);
        spmm2_kernel<false, false><<<grid, 256, 0, stream>>>(pA, edges, offs, pB, n_nodes);
        spmm2_kernel<false, false><<<grid, 256, 0, stream>>>(pB, edges, offs, pA, n_nodes);
        spmm2_kernel<false, false><<<grid, 256, 0, stream>>>(pA, edges, offs, pB, n_nodes);
        spmm2_kernel<false, true ><<<grid, 256, 0, stream>>>(pB, edges, offs, out, n_nodes);
    }
}

// Round 7
// 238.603 us; speedup vs baseline: 6.1002x; 1.0232x over previous
//
#include <hip/hip_runtime.h>
#include <hip/hip_fp16.h>
#include <stdint.h>

#define D_FEAT 64
#define CH 4096         // edges per chunk in hist/place
#define BKT_BITS 8      // 256 rows per bucket

// ---------------- bucket histogram per chunk ----------------
__global__ __launch_bounds__(256) void bhist_kernel(const int* __restrict__ rows,
                                                    int* __restrict__ block_hist,
                                                    int n_edges, int nb) {
    __shared__ int cnt[256];
    cnt[threadIdx.x] = 0;
    __syncthreads();
    int beg = blockIdx.x * CH;
    int end = min(beg + CH, n_edges);
    for (int i = beg + threadIdx.x; i < end; i += 256)
        atomicAdd(&cnt[rows[i] >> BKT_BITS], 1);
    __syncthreads();
    if (threadIdx.x < nb)
        block_hist[blockIdx.x * nb + threadIdx.x] = cnt[threadIdx.x];
}

// ---------------- parallel scan: per-bucket column over chunks (nchunks <= 512) ----------------
__global__ __launch_bounds__(256) void bscan1_kernel(int* __restrict__ block_hist,
                                                     int* __restrict__ btot,
                                                     int nchunks, int nb) {
    __shared__ int buf[256];
    int j = blockIdx.x;
    int t = threadIdx.x;
    int c0 = 2 * t, c1 = 2 * t + 1;
    int v0 = (c0 < nchunks) ? block_hist[(size_t)c0 * nb + j] : 0;
    int v1 = (c1 < nchunks) ? block_hist[(size_t)c1 * nb + j] : 0;
    int loc = v0 + v1;
    buf[t] = loc;
    __syncthreads();
    for (int off = 1; off < 256; off <<= 1) {
        int add = (t >= off) ? buf[t - off] : 0;
        __syncthreads();
        buf[t] += add;
        __syncthreads();
    }
    int excl = buf[t] - loc;
    if (c0 < nchunks) block_hist[(size_t)c0 * nb + j] = excl;
    if (c1 < nchunks) block_hist[(size_t)c1 * nb + j] = excl + v0;
    if (t == 255) btot[j] = buf[255];
}

__global__ __launch_bounds__(256) void bscan2_kernel(const int* __restrict__ btot,
                                                     int* __restrict__ bbase, int nb) {
    __shared__ int buf[256];
    int t = threadIdx.x;
    int v = (t < nb) ? btot[t] : 0;
    buf[t] = v;
    __syncthreads();
    for (int off = 1; off < 256; off <<= 1) {
        int add = (t >= off) ? buf[t - off] : 0;
        __syncthreads();
        buf[t] += add;
        __syncthreads();
    }
    if (t < nb) {
        bbase[t] = buf[t] - v;
        if (t == nb - 1) bbase[nb] = buf[t];
    }
}

// ---------------- place edges into bucket-contiguous mid array ----------------
__global__ __launch_bounds__(256) void bplace_kernel(const float* __restrict__ vals,
                                                     const int* __restrict__ rows,
                                                     const int* __restrict__ cols,
                                                     const int* __restrict__ block_hist,
                                                     const int* __restrict__ bbase,
                                                     uint2* __restrict__ mid,
                                                     int n_edges, int nb) {
    __shared__ int cnt[256];
    __shared__ int base[256];
    int t = threadIdx.x;
    cnt[t] = 0;
    if (t < nb) base[t] = bbase[t] + block_hist[(size_t)blockIdx.x * nb + t];
    __syncthreads();
    int beg = blockIdx.x * CH;
    int end = min(beg + CH, n_edges);
    for (int i = beg + t; i < end; i += 256) {
        int r = rows[i];
        int b = r >> BKT_BITS;
        int lrank = atomicAdd(&cnt[b], 1);
        __half hv = __float2half_rn(vals[i]);
        unsigned short vb = *reinterpret_cast<unsigned short*>(&hv);
        uint32_t packed = (uint32_t)(cols[i] & 0xFFFF) | ((uint32_t)vb << 16);
        mid[base[b] + lrank] = make_uint2(packed, (uint32_t)r);
    }
}

// ---------------- per-bucket counting sort by row + fused offs[] (no rank stash) ----------------
__global__ __launch_bounds__(256) void bsort_kernel(const uint2* __restrict__ mid,
                                                    const int* __restrict__ bbase,
                                                    uint32_t* __restrict__ edges,
                                                    int* __restrict__ offs,
                                                    int n_nodes, int nb) {
    __shared__ int cnt[256];
    __shared__ int start[256];
    __shared__ int buf[256];
    int j = blockIdx.x;
    int t = threadIdx.x;
    int lo = bbase[j];
    int hi = bbase[j + 1];
    cnt[t] = 0;
    __syncthreads();
    const uint32_t RMASK = (1u << BKT_BITS) - 1u;
    // pass 1: count per row
    for (int i = lo + t; i < hi; i += 256)
        atomicAdd(&cnt[mid[i].y & RMASK], 1);
    __syncthreads();
    int v = cnt[t];
    buf[t] = v;
    __syncthreads();
    for (int off = 1; off < 256; off <<= 1) {
        int add = (t >= off) ? buf[t - off] : 0;
        __syncthreads();
        buf[t] += add;
        __syncthreads();
    }
    int st = buf[t] - v;  // exclusive prefix within bucket
    start[t] = st;
    int rg = (j << BKT_BITS) + t;
    if (rg <= n_nodes) offs[rg] = lo + st;
    __syncthreads();
    cnt[t] = 0;
    __syncthreads();
    // pass 2: re-read own entries; rank via fresh counter (any within-row order is fine)
    for (int i = lo + t; i < hi; i += 256) {
        uint2 e = mid[i];
        int r = (int)(e.y & RMASK);
        int rank = atomicAdd(&cnt[r], 1);
        edges[lo + start[r] + rank] = e.x;
    }
}

// ---------------- x (f32 row-major) -> split-layout fp16 ----------------
// split layout (half2 units): dst[half * n*16 + node*16 + gl] holds feats (half*32 + 2gl, +1)
__global__ __launch_bounds__(256) void xcast_kernel(const float2* __restrict__ x,
                                                    __half2* __restrict__ dst, int n_nodes) {
    int t = blockIdx.x * 256 + threadIdx.x;
    int total = n_nodes * 32;
    if (t >= total) return;
    int node = t >> 5;
    int k = t & 31;
    int half = k >> 4;
    int gl = k & 15;
    float2 v = x[(size_t)node * 32 + half * 16 + gl];
    dst[(size_t)half * n_nodes * 16 + (size_t)node * 16 + gl] = __float22half2_rn(v);
}

// ---------------- SpMM: split layout, 4 rows/wave (16 lanes each), XCD-partitioned halves ----

__device__ __forceinline__ float unpack_val(uint32_t u) {
    __half_raw hr;
    hr.x = (unsigned short)(u >> 16);
    return __half2float(__half(hr));
}

template <int K>
__device__ __forceinline__ void gfmaS(const __half2* __restrict__ hv,
                                      const uint32_t* __restrict__ edges,
                                      int j, size_t halfbase, int gl, float2& acc) {
    uint32_t u[K];
#pragma unroll
    for (int k = 0; k < K; ++k) u[k] = edges[j + k];
    float2 hh[K];
#pragma unroll
    for (int k = 0; k < K; ++k) {
        size_t c = (size_t)(u[k] & 0xFFFF);
        hh[k] = __half22float2(hv[halfbase + c * 16 + gl]);
    }
#pragma unroll
    for (int k = 0; k < K; ++k) {
        float v = unpack_val(u[k]);
        acc.x = fmaf(v, hh[k].x, acc.x);
        acc.y = fmaf(v, hh[k].y, acc.y);
    }
}

template <bool OUT_F32>
__global__ __launch_bounds__(256) void spmm_split_kernel(const __half2* __restrict__ hv,
                                                         const uint32_t* __restrict__ edges,
                                                         const int* __restrict__ offs,
                                                         void* __restrict__ outv,
                                                         int n_nodes, int ntiles) {
    int bid = blockIdx.x;
    int half = (bid >> 2) & 1;                 // blockIdx%8 in {0..3}->half0, {4..7}->half1
    int tile = (bid >> 3) * 4 + (bid & 3);
    if (tile >= ntiles) return;
    int t = threadIdx.x;
    int warp = t >> 6;
    int lane = t & 63;
    int grp = lane >> 4;      // 4 row-groups per wave
    int gl = lane & 15;       // half2 index within 32-feat half
    int row = tile * 16 + warp * 4 + grp;
    if (row >= n_nodes) return;
    size_t halfbase = (size_t)half * n_nodes * 16;
    int beg = offs[row];
    int end = offs[row + 1];
    float2 acc = make_float2(0.f, 0.f);
    int j = beg;
    for (; j + 8 <= end; j += 8) gfmaS<8>(hv, edges, j, halfbase, gl, acc);
    if (j + 4 <= end) { gfmaS<4>(hv, edges, j, halfbase, gl, acc); j += 4; }
    for (; j < end; ++j) {
        uint32_t u = edges[j];
        float2 hh = __half22float2(hv[halfbase + (size_t)(u & 0xFFFF) * 16 + gl]);
        float v = unpack_val(u);
        acc.x = fmaf(v, hh.x, acc.x);
        acc.y = fmaf(v, hh.y, acc.y);
    }
    if (OUT_F32) {
        // row-major f32 output: feature pair (half*32 + 2gl, +1)
        ((float2*)outv)[(size_t)row * 32 + half * 16 + gl] = acc;
    } else {
        ((__half2*)outv)[halfbase + (size_t)row * 16 + gl] = __float22half2_rn(acc);
    }
}

// ---------------- fallback (atomic path) ----------------

__global__ void spmm_atomic_kernel(const float* __restrict__ h,
                                   const float* __restrict__ vals,
                                   const int* __restrict__ rows,
                                   const int* __restrict__ cols,
                                   float* __restrict__ out,
                                   int n_edges) {
    long long tid = (long long)blockIdx.x * blockDim.x + threadIdx.x;
    int e = (int)(tid >> 6);
    int d = (int)(tid & 63);
    if (e >= n_edges) return;
    float m = vals[e] * h[(size_t)cols[e] * D_FEAT + d];
    atomicAdd(&out[(size_t)rows[e] * D_FEAT + d], m);
}

extern "C" void kernel_launch(void* const* d_in, const int* in_sizes, int n_in,
                              void* d_out, int out_size, void* d_ws, size_t ws_size,
                              hipStream_t stream) {
    const float* x    = (const float*)d_in[0];
    const float* vals = (const float*)d_in[1];
    const int*   rows = (const int*)d_in[2];
    const int*   cols = (const int*)d_in[3];

    int n_nodes = in_sizes[0] / D_FEAT;
    int n_edges = in_sizes[1];

    float* out = (float*)d_out;

    size_t buf_bytes_f32 = (size_t)n_nodes * D_FEAT * sizeof(float);
    size_t buf_bytes_f16 = (size_t)n_nodes * D_FEAT * sizeof(__half);

    auto align_up = [](size_t v) { return (v + 255) & ~(size_t)255; };

    int nb = (n_nodes + 255) >> BKT_BITS;
    int nchunks = (n_edges + CH - 1) / CH;

    size_t pa_b   = align_up(buf_bytes_f16);
    size_t pb_b   = align_up(buf_bytes_f16);
    size_t mid_b  = align_up((size_t)n_edges * sizeof(uint2));
    size_t region1 = pa_b + pb_b;
    if (mid_b > region1) region1 = mid_b;          // mid aliases pA/pB (dead before xcast/spmm)
    size_t edges_b = align_up((size_t)n_edges * sizeof(uint32_t));
    size_t offs_b  = align_up((size_t)(n_nodes + 1) * sizeof(int));
    size_t bh_b    = align_up((size_t)nchunks * nb * sizeof(int));
    size_t bb_b    = align_up((size_t)(nb + 1) * sizeof(int));
    size_t bt_b    = align_up(256 * sizeof(int));
    size_t need = region1 + edges_b + offs_b + bh_b + bb_b + bt_b;

    if (ws_size < need || n_nodes > 65536 || nchunks > 512) {
        float* ws = (float*)d_ws;
        float* dsts[5] = {out, ws, out, ws, out};
        long long total_threads = (long long)n_edges * D_FEAT;
        int block = 256;
        int grid = (int)((total_threads + block - 1) / block);
        const float* src = x;
        for (int s = 0; s < 5; ++s) {
            hipMemsetAsync(dsts[s], 0, buf_bytes_f32, stream);
            spmm_atomic_kernel<<<grid, block, 0, stream>>>(src, vals, rows, cols,
                                                           dsts[s], n_edges);
            src = dsts[s];
        }
        return;
    }

    char* p = (char*)d_ws;
    char* r1 = p;                        p += region1;
    uint32_t* edges      = (uint32_t*)p; p += edges_b;
    int*      offs       = (int*)p;      p += offs_b;
    int*      block_hist = (int*)p;      p += bh_b;
    int*      bbase      = (int*)p;      p += bb_b;
    int*      btot       = (int*)p;      p += bt_b;

    __half2* pA = (__half2*)r1;
    __half2* pB = (__half2*)(r1 + pa_b);
    uint2*   mid = (uint2*)r1;           // aliases pA/pB; consumed before they're written

    // ---- build row-sorted packed edge list + offs ----
    bhist_kernel<<<nchunks, 256, 0, stream>>>(rows, block_hist, n_edges, nb);
    bscan1_kernel<<<nb, 256, 0, stream>>>(block_hist, btot, nchunks, nb);
    bscan2_kernel<<<1, 256, 0, stream>>>(btot, bbase, nb);
    bplace_kernel<<<nchunks, 256, 0, stream>>>(vals, rows, cols, block_hist, bbase,
                                               mid, n_edges, nb);
    bsort_kernel<<<nb, 256, 0, stream>>>(mid, bbase, edges, offs, n_nodes, nb);

    // ---- convert x to split-fp16, then 5 split SpMM steps ----
    {
        int total = n_nodes * 32;
        xcast_kernel<<<(total + 255) / 256, 256, 0, stream>>>((const float2*)x, pA, n_nodes);

        int ntiles = (n_nodes + 15) / 16;
        int grid = ((ntiles + 3) / 4) * 8;
        // pA -> pB -> pA -> pB -> pA -> out
        spmm_split_kernel<false><<<grid, 256, 0, stream>>>(pA, edges, offs, pB, n_nodes, ntiles);
        spmm_split_kernel<false><<<grid, 256, 0, stream>>>(pB, edges, offs, pA, n_nodes, ntiles);
        spmm_split_kernel<false><<<grid, 256, 0, stream>>>(pA, edges, offs, pB, n_nodes, ntiles);
        spmm_split_kernel<false><<<grid, 256, 0, stream>>>(pB, edges, offs, pA, n_nodes, ntiles);
        spmm_split_kernel<true ><<<grid, 256, 0, stream>>>(pA, edges, offs, out, n_nodes, ntiles);
    }
}